// Round 3
// baseline (414.136 us; speedup 1.0000x reference)
//
#include <hip/hip_runtime.h>
#include <cstdint>

// y[16384,2048] = x(f32) @ W(int8-valued int32, [in,out]) * scale[1,2048]
// R3: 32x32x16 MFMA (2495 TF ceiling vs 2075 for 16x16) + XOR-swizzled LDS
// (16B-granular, realized via DMA lane->global-address permutation) to kill
// the 1.7e7 bank conflicts seen in R2.

#define M_TOK 16384
#define K_DIM 2048
#define N_DIM 2048
#define BK 32

typedef _Float16 f16;
typedef f16 f16x4 __attribute__((ext_vector_type(4)));
typedef f16 f16x8 __attribute__((ext_vector_type(8)));
typedef float f32x16 __attribute__((ext_vector_type(16)));

// ---------------------------------------------------------------------------
// Pre-pass 1: x fp32 -> f16 (RNE). Memory-bound: 134MB read + 67MB write.
// ---------------------------------------------------------------------------
__global__ void convert_x_kernel(const float* __restrict__ x, f16* __restrict__ xh) {
  const int n8 = (M_TOK * K_DIM) / 8;
  const int stride = gridDim.x * blockDim.x;
  for (int i = blockIdx.x * blockDim.x + threadIdx.x; i < n8; i += stride) {
    float4 v0 = ((const float4*)x)[i * 2];
    float4 v1 = ((const float4*)x)[i * 2 + 1];
    f16x8 h;
    h[0] = (f16)v0.x; h[1] = (f16)v0.y; h[2] = (f16)v0.z; h[3] = (f16)v0.w;
    h[4] = (f16)v1.x; h[5] = (f16)v1.y; h[6] = (f16)v1.z; h[7] = (f16)v1.w;
    ((f16x8*)xh)[i] = h;
  }
}

// ---------------------------------------------------------------------------
// Pre-pass 2: W int32 [K][N] -> W^T f16 [N][K] (tiled transpose; exact in f16)
// ---------------------------------------------------------------------------
__global__ void convert_w_kernel(const int* __restrict__ w, f16* __restrict__ wt) {
  __shared__ f16 tile[64][68];             // [n_local][k_local], padded
  const int tid = threadIdx.x;
  const int nb = blockIdx.x * 64;
  const int kb = blockIdx.y * 64;
  const int cq = tid & 15;
  const int rr = tid >> 4;

#pragma unroll
  for (int g = 0; g < 4; ++g) {
    int krow = g * 16 + rr;
    const int* p = w + (size_t)(kb + krow) * N_DIM + nb + cq * 4;
    int4 v = *(const int4*)p;              // coalesced along n
    tile[cq * 4 + 0][krow] = (f16)(float)v.x;
    tile[cq * 4 + 1][krow] = (f16)(float)v.y;
    tile[cq * 4 + 2][krow] = (f16)(float)v.z;
    tile[cq * 4 + 3][krow] = (f16)(float)v.w;
  }
  __syncthreads();
#pragma unroll
  for (int g = 0; g < 4; ++g) {
    int nrow = g * 16 + rr;
    f16x4 o;
#pragma unroll
    for (int j = 0; j < 4; ++j) o[j] = tile[nrow][cq * 4 + j];
    *(f16x4*)(wt + (size_t)(nb + nrow) * K_DIM + kb + cq * 4) = o;  // coalesced along k
  }
}

// ---------------------------------------------------------------------------
// Main GEMM. 128x128 block tile, 4 waves (2x2), wave = 2x2 of 32x32x16 MFMA.
// LDS tiles [row][64B] with 16B-slot swizzle p = c ^ ((row>>1)&3).
// ---------------------------------------------------------------------------
__device__ __forceinline__ void async_load16(const void* g, void* l) {
  __builtin_amdgcn_global_load_lds((__attribute__((address_space(1))) void*)g,
                                   (__attribute__((address_space(3))) void*)l,
                                   16, 0, 0);
}

__global__ __launch_bounds__(256) void gemm_f16(
    const f16* __restrict__ xh, const f16* __restrict__ wt,
    const float* __restrict__ scale, float* __restrict__ out) {
  __shared__ __align__(16) f16 sA[128 * BK];    // 8KB, row = 64B = 4 x 16B slots
  __shared__ __align__(16) f16 sB[128 * BK];    // 8KB

  const int tid = threadIdx.x;
  const int wave = tid >> 6;
  const int lane = tid & 63;
  const int m0 = blockIdx.y * 128;
  const int n0 = blockIdx.x * 128;
  const int wm = (wave & 1) * 64;
  const int wn = (wave >> 1) * 64;

  // ---- DMA staging with swizzle-compensating global addresses ----
  // Wave fills physical 1KB chunks {2w, 2w+1} of each tile.
  // lane i -> physical (row = q*16 + i/4, slot p = i&3); logical chunk
  // stored there is c = p ^ ((row>>1)&3)  -> global k-offset c*8 elements.
  const int q0 = wave * 2;
  const int rowS = q0 * 16 + (lane >> 2);            // physical row, chunk q0
  const int cS = (lane & 3) ^ ((rowS >> 1) & 3);     // logical 16B chunk
  // row+16 has the same swizzle key ((row>>1)+8 ≡ same mod 4)
  const f16* gA0 = xh + (size_t)(m0 + rowS) * K_DIM + cS * 8;
  const f16* gA1 = gA0 + (size_t)16 * K_DIM;
  const f16* gB0 = wt + (size_t)(n0 + rowS) * K_DIM + cS * 8;
  const f16* gB1 = gB0 + (size_t)16 * K_DIM;
  f16* lA0 = sA + q0 * 512;  f16* lA1 = lA0 + 512;
  f16* lB0 = sB + q0 * 512;  f16* lB1 = lB0 + 512;

  // ---- MFMA fragment read addresses (loop-invariant, swizzled) ----
  // 32x32x16: A[m=lane&31][k=(lane>>5)*8+j]; frag 16B = logical chunk
  // c = kh*2 + (lane>>5) of row wm+mt*32+(lane&31).
  const int fr = lane & 31;
  const int kq = lane >> 5;                          // 0/1
  const f16* aAddr[2][2];
  const f16* bAddr[2][2];
#pragma unroll
  for (int mt = 0; mt < 2; ++mt)
#pragma unroll
    for (int kh = 0; kh < 2; ++kh) {
      int rA = wm + mt * 32 + fr;
      int rB = wn + mt * 32 + fr;
      int cA = (kh * 2 + kq) ^ ((rA >> 1) & 3);
      int cB = (kh * 2 + kq) ^ ((rB >> 1) & 3);
      aAddr[mt][kh] = sA + rA * BK + cA * 8;
      bAddr[mt][kh] = sB + rB * BK + cB * 8;
    }

  f32x16 acc[2][2] = {};

  for (int k0 = 0; k0 < K_DIM; k0 += BK) {
    async_load16(gA0 + k0, lA0);
    async_load16(gA1 + k0, lA1);
    async_load16(gB0 + k0, lB0);
    async_load16(gB1 + k0, lB1);
    __syncthreads();   // drains DMA (vmcnt) -> data visible

    f16x8 a[2][2], b[2][2];
#pragma unroll
    for (int mt = 0; mt < 2; ++mt)
#pragma unroll
      for (int kh = 0; kh < 2; ++kh) {
        a[mt][kh] = *(const f16x8*)aAddr[mt][kh];
        b[mt][kh] = *(const f16x8*)bAddr[mt][kh];
      }
#pragma unroll
    for (int kh = 0; kh < 2; ++kh)
#pragma unroll
      for (int mt = 0; mt < 2; ++mt)
#pragma unroll
        for (int nt = 0; nt < 2; ++nt)
          acc[mt][nt] = __builtin_amdgcn_mfma_f32_32x32x16_f16(
              a[mt][kh], b[nt][kh], acc[mt][nt], 0, 0, 0);
    __syncthreads();   // protect LDS from next iteration's DMA
  }

  // ---- Epilogue: 32x32 C/D layout col=lane&31, row=(reg&3)+8*(reg>>2)+4*(lane>>5)
#pragma unroll
  for (int nt = 0; nt < 2; ++nt) {
    int col = n0 + wn + nt * 32 + fr;
    float s = scale[col];
#pragma unroll
    for (int mt = 0; mt < 2; ++mt) {
      int rbase = m0 + wm + mt * 32 + 4 * kq;
#pragma unroll
      for (int reg = 0; reg < 16; ++reg) {
        int row = rbase + (reg & 3) + 8 * (reg >> 2);
        out[(size_t)row * N_DIM + col] = acc[mt][nt][reg] * s;
      }
    }
  }
}

// ---------------------------------------------------------------------------
extern "C" void kernel_launch(void* const* d_in, const int* in_sizes, int n_in,
                              void* d_out, int out_size, void* d_ws, size_t ws_size,
                              hipStream_t stream) {
  const float* x     = (const float*)d_in[0];
  const float* scale = (const float*)d_in[1];
  const int* w       = (const int*)d_in[2];   // integer inputs arrive as int32
  float* out         = (float*)d_out;

  // workspace: x_h f16 (64MB) | W^T f16 (8MB)
  char* ws = (char*)d_ws;
  f16* xh = (f16*)ws;
  f16* wt = (f16*)(ws + (size_t)M_TOK * K_DIM * 2);

  convert_x_kernel<<<8192, 256, 0, stream>>>(x, xh);
  convert_w_kernel<<<dim3(N_DIM / 64, K_DIM / 64), 256, 0, stream>>>(w, wt);
  gemm_f16<<<dim3(N_DIM / 128, M_TOK / 128), 256, 0, stream>>>(xh, wt, scale, out);
}